// Round 3
// baseline (144.004 us; speedup 1.0000x reference)
//
#include <hip/hip_runtime.h>

#define WAVES 16
#define BLOCK (WAVES * 64)

// B=16384, M=41, NMODES=2, HDIM=10, S=419 (runtime from in_sizes)
// lane = batch element (64/block), 16 waves iterate s cyclically (s=wave; s+=16).
// W1 contraction done in TWO PASSES over s (o in [0,5) then [5,10)) so the hot
// accumulator set is 20 floats/pass -> fits arch VGPRs, no v_accvgpr traffic
// (round-2 counters showed 2.9x VALU inflation from AGPR round-trips at 40 acc).
// Reduced basis A[o][p] = D[o,0,p] + D[o,1,1-p] (epilogue only needs this sum).
// E staged in LDS column-major [k][lane] as float4 -> ds_read_b128.
// All s-indexed loads are wave-uniform -> scalar s_load broadcasts.

__global__ __launch_bounds__(BLOCK, 4) void eqsonn_kernel(
    const float* __restrict__ x,      // [B,41,2,2]
    const float* __restrict__ task,   // [B,4]
    const float* __restrict__ pbcC,   // [S,2]
    const float* __restrict__ W1,     // [10,2,S,2]
    const float* __restrict__ b1,     // [10,2]
    const float* __restrict__ W2,     // [10,2,41,2]
    const float* __restrict__ b2,     // [10,2]
    const int* __restrict__ m_idx,    // [S]
    const int* __restrict__ n_idx,    // [S]
    float* __restrict__ out,          // [B,2,2]
    int B, int S)
{
    __shared__ float4 Esh[41 * 64];    // 41984 B
    __shared__ float2 D2sh[40 * 64];   // 20480 B (f2 dots; later aliased as acc)

    const int tid  = threadIdx.x;
    const int lane = tid & 63;
    const int wave = tid >> 6;
    const int b0   = blockIdx.x * 64;
    const int b    = b0 + lane;

    // ---- stage E: coalesced float4 global loads -> LDS column-major ----
    for (int e = tid; e < 41 * 64; e += BLOCK) {
        int bb = e / 41;
        int k  = e - bb * 41;
        int bs = b0 + bb; if (bs > B - 1) bs = B - 1;
        Esh[k * 64 + bb] = ((const float4*)x)[(size_t)bs * 41 + k];
    }
    __syncthreads();

    // ---- f2 dots: d = (o*2+i)*2+p ; wave handles d = wave + 16r ----
    {
        float ar[3] = {0.f, 0.f, 0.f}, ai[3] = {0.f, 0.f, 0.f};
        int du = __builtin_amdgcn_readfirstlane(wave);
        for (int k = 0; k < 41; k++) {
            float4 E4 = Esh[k * 64 + lane];
#pragma unroll
            for (int r = 0; r < 3; r++) {
                int d = du + 16 * r;
                if (d < 40) {
                    int o = d >> 2, i = (d >> 1) & 1, p = d & 1;
                    float wr = W2[((o * 2 + i) * 41 + k) * 2 + 0];
                    float wi = W2[((o * 2 + i) * 41 + k) * 2 + 1];
                    float er = p ? E4.z : E4.x;
                    float ei = p ? E4.w : E4.y;
                    ar[r] += wr * er - wi * ei;
                    ai[r] += wr * ei + wi * er;
                }
            }
        }
#pragma unroll
        for (int r = 0; r < 3; r++) {
            int d = du + 16 * r;
            if (d < 40) D2sh[d * 64 + lane] = make_float2(ar[r], ai[r]);
        }
    }

    const int su = __builtin_amdgcn_readfirstlane(wave);

    // ---- pass 1: pbc + A[0..4] (20 hot accumulator floats) ----
    float A1[5][4];
#pragma unroll
    for (int o = 0; o < 5; o++) { A1[o][0] = A1[o][1] = A1[o][2] = A1[o][3] = 0.f; }
    float pbc[4] = {0.f, 0.f, 0.f, 0.f};

    for (int s = su; s < S; s += WAVES) {
        int m = m_idx[s];
        int n = n_idx[s];
        float Cr = pbcC[s * 2 + 0], Ci = pbcC[s * 2 + 1];
        float4 Em = Esh[(20 + m) * 64 + lane];
        float4 Eb = Esh[(20 + m + n) * 64 + lane];
        float4 En = Esh[(20 + n) * 64 + lane];
        float sr = Em.x * Eb.x + Em.y * Eb.y + Em.z * Eb.z + Em.w * Eb.w;
        float si = Em.y * Eb.x - Em.x * Eb.y + Em.w * Eb.z - Em.z * Eb.w;
        float F0r = sr * En.x - si * En.y, F0i = sr * En.y + si * En.x;
        float F1r = sr * En.z - si * En.w, F1i = sr * En.w + si * En.z;
        pbc[0] += F0r * Cr - F0i * Ci; pbc[1] += F0r * Ci + F0i * Cr;
        pbc[2] += F1r * Cr - F1i * Ci; pbc[3] += F1r * Ci + F1i * Cr;
#pragma unroll
        for (int o = 0; o < 5; o++) {
            float w0r = W1[((size_t)(o * 2 + 0) * S + s) * 2 + 0];
            float w0i = W1[((size_t)(o * 2 + 0) * S + s) * 2 + 1];
            float w1r = W1[((size_t)(o * 2 + 1) * S + s) * 2 + 0];
            float w1i = W1[((size_t)(o * 2 + 1) * S + s) * 2 + 1];
            A1[o][0] += w0r * F0r - w0i * F0i + w1r * F1r - w1i * F1i;
            A1[o][1] += w0r * F0i + w0i * F0r + w1r * F1i + w1i * F1r;
            A1[o][2] += w0r * F1r - w0i * F1i + w1r * F0r - w1i * F0i;
            A1[o][3] += w0r * F1i + w0i * F1r + w1r * F0i + w1i * F0r;
        }
    }

    // ---- pass 2: A[5..9] (20 hot accumulator floats; A1/pbc cold) ----
    float A2[5][4];
#pragma unroll
    for (int o = 0; o < 5; o++) { A2[o][0] = A2[o][1] = A2[o][2] = A2[o][3] = 0.f; }

    for (int s = su; s < S; s += WAVES) {
        int m = m_idx[s];
        int n = n_idx[s];
        float4 Em = Esh[(20 + m) * 64 + lane];
        float4 Eb = Esh[(20 + m + n) * 64 + lane];
        float4 En = Esh[(20 + n) * 64 + lane];
        float sr = Em.x * Eb.x + Em.y * Eb.y + Em.z * Eb.z + Em.w * Eb.w;
        float si = Em.y * Eb.x - Em.x * Eb.y + Em.w * Eb.z - Em.z * Eb.w;
        float F0r = sr * En.x - si * En.y, F0i = sr * En.y + si * En.x;
        float F1r = sr * En.z - si * En.w, F1i = sr * En.w + si * En.z;
#pragma unroll
        for (int o = 0; o < 5; o++) {
            float w0r = W1[((size_t)((o + 5) * 2 + 0) * S + s) * 2 + 0];
            float w0i = W1[((size_t)((o + 5) * 2 + 0) * S + s) * 2 + 1];
            float w1r = W1[((size_t)((o + 5) * 2 + 1) * S + s) * 2 + 0];
            float w1i = W1[((size_t)((o + 5) * 2 + 1) * S + s) * 2 + 1];
            A2[o][0] += w0r * F0r - w0i * F0i + w1r * F1r - w1i * F1i;
            A2[o][1] += w0r * F0i + w0i * F0r + w1r * F1i + w1i * F1r;
            A2[o][2] += w0r * F1r - w0i * F1i + w1r * F0r - w1i * F0i;
            A2[o][3] += w0r * F1i + w0i * F1r + w1r * F0i + w1i * F0r;
        }
    }
    __syncthreads();  // f2 D2 writes visible; all waves past their loops

    // ---- Bm from shared D2, partial term (real-linear in partial A) ----
    float t[4] = {0.f, 0.f, 0.f, 0.f};
#pragma unroll
    for (int o = 0; o < 10; o++) {
        float2 d00 = D2sh[((o * 2 + 0) * 2 + 0) * 64 + lane];
        float2 d01 = D2sh[((o * 2 + 0) * 2 + 1) * 64 + lane];
        float2 d10 = D2sh[((o * 2 + 1) * 2 + 0) * 64 + lane];
        float2 d11 = D2sh[((o * 2 + 1) * 2 + 1) * 64 + lane];
        float b2r = b2[o * 2 + 0], b2i = b2[o * 2 + 1];
        float B0r = d00.x + d11.x + b2r, B0i = d00.y + d11.y + b2i;
        float B1r = d01.x + d10.x + b2r, B1i = d01.y + d10.y + b2i;
        float A0r = (o < 5) ? A1[o][0] : A2[o - 5][0];
        float A0i = (o < 5) ? A1[o][1] : A2[o - 5][1];
        float A1r = (o < 5) ? A1[o][2] : A2[o - 5][2];
        float A1i = (o < 5) ? A1[o][3] : A2[o - 5][3];
        if (wave == 0) {  // b1 contribution exactly once
            float b1r = b1[o * 2 + 0], b1i = b1[o * 2 + 1];
            A0r += b1r; A0i += b1i;
            A1r += b1r; A1i += b1i;
        }
        // A*B*conj(B) + conj(A)*B*B = 2*Re(A*conj(B)) * B
        float g0 = 2.f * (A0r * B0r + A0i * B0i);
        t[0] += g0 * B0r; t[1] += g0 * B0i;
        float g1 = 2.f * (A1r * B1r + A1i * B1i);
        t[2] += g1 * B1r; t[3] += g1 * B1i;
    }

    // ---- fold P / kP^2 per wave, single float4 partial per (wave,lane) ----
    int bt = (b < B) ? b : (B - 1);
    float dbm = task[(size_t)bt * 4 + 0];
    float P   = exp2f(dbm * 0.33219280948873623f) * 0.5f;   // 10^(dbm/10)/2
    float kP2 = 3.1622776601683794e-05f * P * P;            // 1e-4/sqrt(10)*P^2
    float4 contrib;
    contrib.x = P * pbc[0] + kP2 * t[0];
    contrib.y = P * pbc[1] + kP2 * t[1];
    contrib.z = P * pbc[2] + kP2 * t[2];
    contrib.w = P * pbc[3] + kP2 * t[3];

    __syncthreads();  // everyone done reading D2sh; safe to alias
    float4* acc = (float4*)D2sh;  // [WAVES][64] float4 = 16 KB
    acc[wave * 64 + lane] = contrib;
    __syncthreads();

    if (wave == 0) {
        float4 sum = acc[lane];
#pragma unroll
        for (int w = 1; w < WAVES; w++) {
            float4 c = acc[w * 64 + lane];
            sum.x += c.x; sum.y += c.y; sum.z += c.z; sum.w += c.w;
        }
        if (b < B) {
            float4 Ec = Esh[20 * 64 + lane];  // E[c, :]
            float4 o4;
            o4.x = Ec.x + sum.x;
            o4.y = Ec.y + sum.y;
            o4.z = Ec.z + sum.z;
            o4.w = Ec.w + sum.w;
            ((float4*)out)[b] = o4;
        }
    }
}

extern "C" void kernel_launch(void* const* d_in, const int* in_sizes, int n_in,
                              void* d_out, int out_size, void* d_ws, size_t ws_size,
                              hipStream_t stream) {
    const float* x     = (const float*)d_in[0];
    const float* task  = (const float*)d_in[1];
    const float* pbcC  = (const float*)d_in[2];
    const float* W1    = (const float*)d_in[3];
    const float* b1    = (const float*)d_in[4];
    const float* W2    = (const float*)d_in[5];
    const float* b2    = (const float*)d_in[6];
    const int*   m_idx = (const int*)d_in[7];
    const int*   n_idx = (const int*)d_in[8];
    float* out = (float*)d_out;

    int S = in_sizes[7];             // m_idx element count
    int B = in_sizes[0] / (41 * 2 * 2);

    int grid = (B + 63) / 64;
    eqsonn_kernel<<<grid, BLOCK, 0, stream>>>(x, task, pbcC, W1, b1, W2, b2,
                                              m_idx, n_idx, out, B, S);
}

// Round 4
// 122.515 us; speedup vs baseline: 1.1754x; 1.1754x over previous
//
#include <hip/hip_runtime.h>

typedef short bf16x8 __attribute__((ext_vector_type(8)));
typedef float f32x4  __attribute__((ext_vector_type(4)));

#define WAVES 16
#define BLOCK 1024
#define SPAD 448              // S padded to multiple of 64 (S=419)
#define KDIM (4 * SPAD)       // 1792 real-K (k = 4s + 2c + i)
#define NCHUNK (SPAD / 64)    // 7 chunks of 64 s = 256 K
#define ROWS 80               // real-expanded output rows (o,p,reim)

#define ESH_OFF 0             // E bf16x4, [41][64], 20992 B
#define FCH_OFF 20992         // F chunk bf16 [64 cols][256 k] swizzled, 32768 B
#define D2_OFF  53760         // f2 dots bf16x2 [40][64], 10240 B
#define LDS_BYTES 64000

__device__ __forceinline__ unsigned short f2bf(float f) {
    union { float f; unsigned u; } v; v.f = f;
    unsigned r = v.u + 0x7FFFu + ((v.u >> 16) & 1u);   // RNE
    return (unsigned short)(r >> 16);
}
__device__ __forceinline__ float bf2f(unsigned short h) {
    union { unsigned u; float f; } v; v.u = ((unsigned)h) << 16;
    return v.f;
}

// Build W'[row=(o*4+p*2+r)][k=4s+2c+i] bf16 in d_ws.
// A[o,p] = sum_{i,s} W1[o, i^p, s] * F[i,s] (complex); real expansion:
// c=0 (Re F): r=0 -> Wr, r=1 -> Wi ; c=1 (Im F): r=0 -> -Wi, r=1 -> Wr.
__global__ void prep_w_kernel(const float* __restrict__ W1,
                              unsigned short* __restrict__ Wp, int S) {
    int idx = blockIdx.x * 256 + threadIdx.x;
    if (idx >= ROWS * KDIM) return;
    int row = idx / KDIM;
    int k   = idx - row * KDIM;
    int o = row >> 2, p = (row >> 1) & 1, r = row & 1;
    int s = k >> 2,  c = (k >> 1) & 1,  i = k & 1;
    float v = 0.f;
    if (s < S) {
        int j = i ^ p;
        float wr = W1[((size_t)(o * 2 + j) * S + s) * 2 + 0];
        float wi = W1[((size_t)(o * 2 + j) * S + s) * 2 + 1];
        v = (c == 0) ? (r == 0 ? wr : wi) : (r == 0 ? -wi : wr);
    }
    Wp[idx] = f2bf(v);
}

__global__ __launch_bounds__(BLOCK, 4) void eqsonn_kernel(
    const float* __restrict__ x,      // [B,41,2,2]
    const float* __restrict__ task,   // [B,4]
    const float* __restrict__ pbcC,   // [S,2]
    const unsigned short* __restrict__ Wp, // [80][KDIM] bf16
    const float* __restrict__ b1,     // [10,2]
    const float* __restrict__ W2,     // [10,2,41,2]
    const float* __restrict__ b2,     // [10,2]
    const int* __restrict__ m_idx,    // [S]
    const int* __restrict__ n_idx,    // [S]
    float* __restrict__ out,          // [B,2,2]
    int B, int S)
{
    __shared__ alignas(16) char ldsb[LDS_BYTES];
    ushort4* Esh = (ushort4*)(ldsb + ESH_OFF);   // [k*64 + col]

    const int tid  = threadIdx.x;
    const int lane = tid & 63;
    const int wave = tid >> 6;
    const int b0   = blockIdx.x * 64;
    const int b    = b0 + lane;
    const int quad = lane >> 4;
    const int l15  = lane & 15;

    // ---- stage E (bf16) column-major ----
    for (int e = tid; e < 41 * 64; e += BLOCK) {
        int bb = e / 41, k = e - bb * 41;
        int bs = b0 + bb; if (bs > B - 1) bs = B - 1;
        float4 v = ((const float4*)x)[(size_t)bs * 41 + k];
        ushort4 h;
        h.x = f2bf(v.x); h.y = f2bf(v.y); h.z = f2bf(v.z); h.w = f2bf(v.w);
        Esh[k * 64 + bb] = h;
    }
    __syncthreads();

    // ---- f2 dots (VALU): d=(o*2+i)*2+p, wave handles d = wave+16r ----
    {
        ushort2* D2 = (ushort2*)(ldsb + D2_OFF);
        float ar[3] = {0.f,0.f,0.f}, ai[3] = {0.f,0.f,0.f};
        int du = __builtin_amdgcn_readfirstlane(wave);
        for (int k = 0; k < 41; k++) {
            ushort4 E4 = Esh[k * 64 + lane];
#pragma unroll
            for (int r = 0; r < 3; r++) {
                int d = du + 16 * r;
                if (d < 40) {
                    int o = d >> 2, i2 = (d >> 1) & 1, p = d & 1;
                    float wr = W2[((o * 2 + i2) * 41 + k) * 2 + 0];
                    float wi = W2[((o * 2 + i2) * 41 + k) * 2 + 1];
                    float er = bf2f(p ? E4.z : E4.x);
                    float ei = bf2f(p ? E4.w : E4.y);
                    ar[r] += wr * er - wi * ei;
                    ai[r] += wr * ei + wi * er;
                }
            }
        }
#pragma unroll
        for (int r = 0; r < 3; r++) {
            int d = du + 16 * r;
            if (d < 40) { ushort2 h; h.x = f2bf(ar[r]); h.y = f2bf(ai[r]);
                          D2[d * 64 + lane] = h; }
        }
    }

    // ---- producer/consumer chunk loop over K ----
    // consumer tiles: 5 M-tiles x 4 N-tiles = 20; waves 0..9 take (mt, 2 nts)
    int mt = -1, nt0 = 0;
    if (wave < 10) { mt = wave >> 1; nt0 = (wave & 1) << 1; }
    f32x4 acc0 = {0.f,0.f,0.f,0.f}, acc1 = {0.f,0.f,0.f,0.f};
    float pbc0 = 0.f, pbc1 = 0.f, pbc2 = 0.f, pbc3 = 0.f;
    const int sw4 = __builtin_amdgcn_readfirstlane(wave << 2);

    for (int ch = 0; ch < NCHUNK; ++ch) {
        // producer: this wave fills s_local = sw4..sw4+3 (col = lane)
#pragma unroll
        for (int j = 0; j < 4; ++j) {
            int sl = sw4 + j;
            int s  = ch * 64 + sl;
            ushort4 h; h.x = 0; h.y = 0; h.z = 0; h.w = 0;
            if (s < S) {
                int m = m_idx[s], n = n_idx[s];
                float Cr = pbcC[s * 2 + 0], Ci = pbcC[s * 2 + 1];
                ushort4 EmH = Esh[(20 + m) * 64 + lane];
                ushort4 EbH = Esh[(20 + m + n) * 64 + lane];
                ushort4 EnH = Esh[(20 + n) * 64 + lane];
                float Emx = bf2f(EmH.x), Emy = bf2f(EmH.y), Emz = bf2f(EmH.z), Emw = bf2f(EmH.w);
                float Ebx = bf2f(EbH.x), Eby = bf2f(EbH.y), Ebz = bf2f(EbH.z), Ebw = bf2f(EbH.w);
                float Enx = bf2f(EnH.x), Eny = bf2f(EnH.y), Enz = bf2f(EnH.z), Enw = bf2f(EnH.w);
                float sr = Emx * Ebx + Emy * Eby + Emz * Ebz + Emw * Ebw;
                float si = Emy * Ebx - Emx * Eby + Emw * Ebz - Emz * Ebw;
                float F0r = sr * Enx - si * Eny, F0i = sr * Eny + si * Enx;
                float F1r = sr * Enz - si * Enw, F1i = sr * Enw + si * Enz;
                pbc0 += F0r * Cr - F0i * Ci; pbc1 += F0r * Ci + F0i * Cr;
                pbc2 += F1r * Cr - F1i * Ci; pbc3 += F1r * Ci + F1i * Cr;
                // k-order within s: [ReF0, ReF1, ImF0, ImF1]
                h.x = f2bf(F0r); h.y = f2bf(F1r); h.z = f2bf(F0i); h.w = f2bf(F1i);
            }
            unsigned off = (unsigned)lane * 512u +
                           (((unsigned)sl * 8u) ^ ((unsigned)(lane & 7) * 16u));
            *(ushort4*)(ldsb + FCH_OFF + off) = h;
        }
        __syncthreads();
        if (mt >= 0) {
            const unsigned short* arow =
                Wp + (size_t)(mt * 16 + l15) * KDIM + ch * 256 + quad * 8;
            int colA = nt0 * 16 + l15, colB = colA + 16;
            unsigned baseA = (unsigned)colA * 512u, swzA = (unsigned)(colA & 7) * 16u;
            unsigned baseB = (unsigned)colB * 512u, swzB = (unsigned)(colB & 7) * 16u;
#pragma unroll
            for (int kk = 0; kk < 8; ++kk) {
                bf16x8 af = *(const bf16x8*)(arow + kk * 32);
                unsigned kb = (unsigned)(kk * 64 + quad * 16);
                bf16x8 bfA = *(const bf16x8*)(ldsb + FCH_OFF + baseA + (kb ^ swzA));
                bf16x8 bfB = *(const bf16x8*)(ldsb + FCH_OFF + baseB + (kb ^ swzB));
                acc0 = __builtin_amdgcn_mfma_f32_16x16x32_bf16(af, bfA, acc0, 0, 0, 0);
                acc1 = __builtin_amdgcn_mfma_f32_16x16x32_bf16(af, bfB, acc1, 0, 0, 0);
            }
        }
        __syncthreads();
    }

    // ---- alias Fchunk: pbc partials [16][64] float4 @+0, Ash bf16 [80][64] @+16384
    float4* pAcc = (float4*)(ldsb + FCH_OFF);
    unsigned short* Ash = (unsigned short*)(ldsb + FCH_OFF + 16384);
    pAcc[wave * 64 + lane] = make_float4(pbc0, pbc1, pbc2, pbc3);
    if (mt >= 0) {
        int c0 = nt0 * 16 + l15;
#pragma unroll
        for (int reg = 0; reg < 4; ++reg) {
            int row = mt * 16 + quad * 4 + reg;   // C/D: row=(lane>>4)*4+reg, col=lane&15
            Ash[row * 64 + c0]      = f2bf(acc0[reg]);
            Ash[row * 64 + c0 + 16] = f2bf(acc1[reg]);
        }
    }
    __syncthreads();

    // ---- epilogue: wave 0, lane = batch ----
    if (wave == 0) {
        float p0 = 0.f, p1 = 0.f, p2 = 0.f, p3 = 0.f;
#pragma unroll
        for (int w = 0; w < WAVES; ++w) {
            float4 a = pAcc[w * 64 + lane];
            p0 += a.x; p1 += a.y; p2 += a.z; p3 += a.w;
        }
        ushort2* D2 = (ushort2*)(ldsb + D2_OFF);
        float t0 = 0.f, t1 = 0.f, t2 = 0.f, t3 = 0.f;
#pragma unroll
        for (int o = 0; o < 10; ++o) {
            ushort2 d00 = D2[((o * 2 + 0) * 2 + 0) * 64 + lane];
            ushort2 d01 = D2[((o * 2 + 0) * 2 + 1) * 64 + lane];
            ushort2 d10 = D2[((o * 2 + 1) * 2 + 0) * 64 + lane];
            ushort2 d11 = D2[((o * 2 + 1) * 2 + 1) * 64 + lane];
            float b2r = b2[o * 2 + 0], b2i = b2[o * 2 + 1];
            float B0r = bf2f(d00.x) + bf2f(d11.x) + b2r;
            float B0i = bf2f(d00.y) + bf2f(d11.y) + b2i;
            float B1r = bf2f(d01.x) + bf2f(d10.x) + b2r;
            float B1i = bf2f(d01.y) + bf2f(d10.y) + b2i;
            float b1r = b1[o * 2 + 0], b1i = b1[o * 2 + 1];
            int rb = o * 4;
            float A0r = bf2f(Ash[(rb + 0) * 64 + lane]) + b1r;
            float A0i = bf2f(Ash[(rb + 1) * 64 + lane]) + b1i;
            float A1r = bf2f(Ash[(rb + 2) * 64 + lane]) + b1r;
            float A1i = bf2f(Ash[(rb + 3) * 64 + lane]) + b1i;
            // A*B*conj(B) + conj(A)*B*B = 2*Re(A*conj(B)) * B
            float g0 = 2.f * (A0r * B0r + A0i * B0i);
            t0 += g0 * B0r; t1 += g0 * B0i;
            float g1 = 2.f * (A1r * B1r + A1i * B1i);
            t2 += g1 * B1r; t3 += g1 * B1i;
        }
        if (b < B) {
            float dbm = task[(size_t)b * 4 + 0];
            float P   = exp2f(dbm * 0.33219280948873623f) * 0.5f; // 10^(dbm/10)/2
            float kP2 = 3.1622776601683794e-05f * P * P;          // 1e-4/sqrt(10)*P^2
            float4 Ec = ((const float4*)x)[(size_t)b * 41 + 20];  // fp32 center symbol
            float4 o4;
            o4.x = Ec.x + P * p0 + kP2 * t0;
            o4.y = Ec.y + P * p1 + kP2 * t1;
            o4.z = Ec.z + P * p2 + kP2 * t2;
            o4.w = Ec.w + P * p3 + kP2 * t3;
            ((float4*)out)[b] = o4;
        }
    }
}

extern "C" void kernel_launch(void* const* d_in, const int* in_sizes, int n_in,
                              void* d_out, int out_size, void* d_ws, size_t ws_size,
                              hipStream_t stream) {
    const float* x     = (const float*)d_in[0];
    const float* task  = (const float*)d_in[1];
    const float* pbcC  = (const float*)d_in[2];
    const float* W1    = (const float*)d_in[3];
    const float* b1    = (const float*)d_in[4];
    const float* W2    = (const float*)d_in[5];
    const float* b2    = (const float*)d_in[6];
    const int*   m_idx = (const int*)d_in[7];
    const int*   n_idx = (const int*)d_in[8];
    float* out = (float*)d_out;

    int S = in_sizes[7];
    int B = in_sizes[0] / (41 * 2 * 2);

    unsigned short* Wp = (unsigned short*)d_ws;   // 80*1792*2 = 286720 B

    int prep_elems = ROWS * KDIM;
    prep_w_kernel<<<(prep_elems + 255) / 256, 256, 0, stream>>>(W1, Wp, S);

    int grid = (B + 63) / 64;
    eqsonn_kernel<<<grid, BLOCK, 0, stream>>>(x, task, pbcC, Wp, b1, W2, b2,
                                              m_idx, n_idx, out, B, S);
}